// Round 1
// baseline (678.388 us; speedup 1.0000x reference)
//
#include <hip/hip_runtime.h>

#define HW 128
#define PLANE (HW * HW)

// ---------------- weight transpose: src[o][ik] -> dst[ik][o] ----------------
__global__ __launch_bounds__(256) void transpose_w_kernel(
    const float* __restrict__ src, float* __restrict__ dst, int O, int IK) {
  int idx = blockIdx.x * 256 + threadIdx.x;
  if (idx >= O * IK) return;
  int o = idx / IK, ik = idx - o * IK;
  dst[ik * O + o] = src[idx];
}

// ---------------- conv1: concat(ref,tgt) [128ch] -> hmid [64ch], leakyrelu ----------------
__global__ __launch_bounds__(256) void conv1_kernel(
    const float* __restrict__ ref, const float* __restrict__ tgt,
    const float* __restrict__ w1t, const float* __restrict__ b1,
    float* __restrict__ hmid) {
  __shared__ float tile[16 * 324];  // 16 channels of 18x18
  const int bx = blockIdx.x * 16, by = blockIdx.y * 16, b = blockIdx.z;
  const int tx = threadIdx.x & 15, ty = threadIdx.x >> 4;

  float4 acc[16];
#pragma unroll
  for (int i = 0; i < 16; ++i) acc[i] = make_float4(0.f, 0.f, 0.f, 0.f);

  for (int chunk = 0; chunk < 8; ++chunk) {
    const float* srcb = (chunk < 4) ? ref : tgt;
    const int cbase = (chunk & 3) * 16;
    __syncthreads();
    for (int idx = threadIdx.x; idx < 16 * 324; idx += 256) {
      int icl = idx / 324;
      int rem = idx - icl * 324;
      int yy = rem / 18, xx = rem - yy * 18;
      int gy = by + yy - 1, gx = bx + xx - 1;
      float v = 0.f;
      if ((unsigned)gy < 128u && (unsigned)gx < 128u)
        v = srcb[(b * 64 + cbase + icl) * PLANE + gy * HW + gx];
      tile[idx] = v;
    }
    __syncthreads();
    const int ic0 = chunk * 16;
    for (int icl = 0; icl < 16; ++icl) {
      const float* wbase = w1t + (ic0 + icl) * 9 * 64;
      const float* trow = tile + icl * 324;
#pragma unroll
      for (int k = 0; k < 9; ++k) {
        const int ky = k / 3, kx = k - ky * 3;
        float v = trow[(ty + ky) * 18 + tx + kx];
        const float4* w4 = (const float4*)(wbase + k * 64);
#pragma unroll
        for (int o = 0; o < 16; ++o) {
          float4 w = w4[o];
          acc[o].x = fmaf(v, w.x, acc[o].x);
          acc[o].y = fmaf(v, w.y, acc[o].y);
          acc[o].z = fmaf(v, w.z, acc[o].z);
          acc[o].w = fmaf(v, w.w, acc[o].w);
        }
      }
    }
  }

  const int y = by + ty, x = bx + tx;
#pragma unroll
  for (int o = 0; o < 16; ++o) {
    float vals[4] = {acc[o].x, acc[o].y, acc[o].z, acc[o].w};
#pragma unroll
    for (int c = 0; c < 4; ++c) {
      int oc = o * 4 + c;
      float vv = vals[c] + b1[oc];
      vv = (vv >= 0.f) ? vv : 0.1f * vv;
      hmid[(b * 64 + oc) * PLANE + y * HW + x] = vv;
    }
  }
}

// ---------------- conv2: hmid [64ch] -> offsets [18ch] ----------------
__global__ __launch_bounds__(256) void conv2_kernel(
    const float* __restrict__ hmid, const float* __restrict__ w2t,
    const float* __restrict__ b2, float* __restrict__ offs) {
  __shared__ float tile[16 * 324];
  const int bx = blockIdx.x * 16, by = blockIdx.y * 16, b = blockIdx.z;
  const int tx = threadIdx.x & 15, ty = threadIdx.x >> 4;

  float acc[18];
#pragma unroll
  for (int i = 0; i < 18; ++i) acc[i] = 0.f;

  for (int chunk = 0; chunk < 4; ++chunk) {
    const int cbase = chunk * 16;
    __syncthreads();
    for (int idx = threadIdx.x; idx < 16 * 324; idx += 256) {
      int icl = idx / 324;
      int rem = idx - icl * 324;
      int yy = rem / 18, xx = rem - yy * 18;
      int gy = by + yy - 1, gx = bx + xx - 1;
      float v = 0.f;
      if ((unsigned)gy < 128u && (unsigned)gx < 128u)
        v = hmid[(b * 64 + cbase + icl) * PLANE + gy * HW + gx];
      tile[idx] = v;
    }
    __syncthreads();
    const int ic0 = chunk * 16;
    for (int icl = 0; icl < 16; ++icl) {
      const float* wbase = w2t + ((ic0 + icl) * 9) * 18;
      const float* trow = tile + icl * 324;
#pragma unroll
      for (int k = 0; k < 9; ++k) {
        const int ky = k / 3, kx = k - ky * 3;
        float v = trow[(ty + ky) * 18 + tx + kx];
        const float* w = wbase + k * 18;
#pragma unroll
        for (int o = 0; o < 18; ++o) acc[o] = fmaf(v, w[o], acc[o]);
      }
    }
  }

  const int y = by + ty, x = bx + tx;
#pragma unroll
  for (int o = 0; o < 18; ++o)
    offs[(b * 18 + o) * PLANE + y * HW + x] = acc[o] + b2[o];
}

// ---------------- deformable conv: gather + 64x(64*9) matmul ----------------
__global__ __launch_bounds__(256) void deform_kernel(
    const float* __restrict__ tgt, const float* __restrict__ offs,
    const float* __restrict__ wdt, float* __restrict__ out) {
  const int bx = blockIdx.x * 16, by = blockIdx.y * 16, b = blockIdx.z;
  const int tx = threadIdx.x & 15, ty = threadIdx.x >> 4;
  const int x = bx + tx, y = by + ty;

  float4 acc[16];
#pragma unroll
  for (int i = 0; i < 16; ++i) acc[i] = make_float4(0.f, 0.f, 0.f, 0.f);

  const float* tb = tgt + b * 64 * PLANE;

  for (int kk = 0; kk < 9; ++kk) {
    float dy = offs[(b * 18 + kk * 2) * PLANE + y * HW + x];
    float dx = offs[(b * 18 + kk * 2 + 1) * PLANE + y * HW + x];
    float ys = (float)(y + (kk / 3) - 1) + dy;
    float xs = (float)(x + (kk % 3) - 1) + dx;
    float y0f = floorf(ys), x0f = floorf(xs);
    float wy = ys - y0f, wx = xs - x0f;
    int y0 = (int)y0f, x0 = (int)x0f;
    int y1 = y0 + 1, x1 = x0 + 1;

    float vy0 = (y0 >= 0 && y0 < HW) ? 1.f : 0.f;
    float vy1 = (y1 >= 0 && y1 < HW) ? 1.f : 0.f;
    float vx0 = (x0 >= 0 && x0 < HW) ? 1.f : 0.f;
    float vx1 = (x1 >= 0 && x1 < HW) ? 1.f : 0.f;

    int y0c = min(max(y0, 0), HW - 1), y1c = min(max(y1, 0), HW - 1);
    int x0c = min(max(x0, 0), HW - 1), x1c = min(max(x1, 0), HW - 1);

    float w00 = (1.f - wy) * (1.f - wx) * vy0 * vx0;
    float w01 = (1.f - wy) * wx * vy0 * vx1;
    float w10 = wy * (1.f - wx) * vy1 * vx0;
    float w11 = wy * wx * vy1 * vx1;

    const float* p00 = tb + y0c * HW + x0c;
    const float* p01 = tb + y0c * HW + x1c;
    const float* p10 = tb + y1c * HW + x0c;
    const float* p11 = tb + y1c * HW + x1c;

    for (int ic = 0; ic < 64; ++ic) {
      int po = ic * PLANE;
      float v = w00 * p00[po] + w01 * p01[po] + w10 * p10[po] + w11 * p11[po];
      const float4* w4 = (const float4*)(wdt + (ic * 9 + kk) * 64);
#pragma unroll
      for (int o = 0; o < 16; ++o) {
        float4 w = w4[o];
        acc[o].x = fmaf(v, w.x, acc[o].x);
        acc[o].y = fmaf(v, w.y, acc[o].y);
        acc[o].z = fmaf(v, w.z, acc[o].z);
        acc[o].w = fmaf(v, w.w, acc[o].w);
      }
    }
  }

#pragma unroll
  for (int o = 0; o < 16; ++o) {
    float vals[4] = {acc[o].x, acc[o].y, acc[o].z, acc[o].w};
#pragma unroll
    for (int c = 0; c < 4; ++c) {
      int oc = o * 4 + c;
      out[(b * 64 + oc) * PLANE + y * HW + x] = vals[c];
    }
  }
}

extern "C" void kernel_launch(void* const* d_in, const int* in_sizes, int n_in,
                              void* d_out, int out_size, void* d_ws, size_t ws_size,
                              hipStream_t stream) {
  const float* ref = (const float*)d_in[0];
  const float* tgt = (const float*)d_in[1];
  const float* w1  = (const float*)d_in[2];
  const float* b1  = (const float*)d_in[3];
  const float* w2  = (const float*)d_in[4];
  const float* b2  = (const float*)d_in[5];
  const float* wd  = (const float*)d_in[6];
  float* out = (float*)d_out;

  char* ws = (char*)d_ws;
  float* hmid = (float*)(ws);                     // 8*64*128*128*4 = 33554432 B
  float* offs = (float*)(ws + 33554432);          // 8*18*128*128*4 =  9437184 B
  float* w1t  = (float*)(ws + 42991616);          // 1152*64*4 = 294912 B
  float* w2t  = (float*)(ws + 43286528);          // 576*18*4  =  41472 B
  float* wdt  = (float*)(ws + 43328000);          // 576*64*4  = 147456 B

  transpose_w_kernel<<<(64 * 1152 + 255) / 256, 256, 0, stream>>>(w1, w1t, 64, 1152);
  transpose_w_kernel<<<(18 * 576 + 255) / 256, 256, 0, stream>>>(w2, w2t, 18, 576);
  transpose_w_kernel<<<(64 * 576 + 255) / 256, 256, 0, stream>>>(wd, wdt, 64, 576);

  dim3 blk(256, 1, 1);
  dim3 grd(HW / 16, HW / 16, 8);
  conv1_kernel<<<grd, blk, 0, stream>>>(ref, tgt, w1t, b1, hmid);
  conv2_kernel<<<grd, blk, 0, stream>>>(hmid, w2t, b2, offs);
  deform_kernel<<<grd, blk, 0, stream>>>(tgt, offs, wdt, out);
}

// Round 2
// 378.969 us; speedup vs baseline: 1.7901x; 1.7901x over previous
//
#include <hip/hip_runtime.h>

#define HW 128
#define PLANE (HW * HW)

typedef __attribute__((ext_vector_type(8))) short bf16x8;
typedef __attribute__((ext_vector_type(4))) float f32x4;

__device__ __forceinline__ unsigned short f2bf(float f) {
  unsigned int u = __float_as_uint(f);
  unsigned int r = (u + 0x7fff + ((u >> 16) & 1)) >> 16;
  return (unsigned short)r;
}

// ---------------- weight transpose: src[o][ik] -> dst[ik][o] (fp32) ----------------
__global__ __launch_bounds__(256) void transpose_w_kernel(
    const float* __restrict__ src, float* __restrict__ dst, int O, int IK) {
  int idx = blockIdx.x * 256 + threadIdx.x;
  if (idx >= O * IK) return;
  int o = idx / IK, ik = idx - o * IK;
  dst[ik * O + o] = src[idx];
}

// ---------------- pack w1 fp32 [64][128][3][3] -> bf16 B'[(k>>3)*64+n][k&7], k=tap*128+ic ----------------
__global__ __launch_bounds__(256) void pack_w1_kernel(
    const float* __restrict__ w1, unsigned short* __restrict__ w1p) {
  int idx = blockIdx.x * 256 + threadIdx.x;
  if (idx >= 1152 * 64) return;
  int k = idx >> 6, n = idx & 63;
  int tap = k >> 7, ic = k & 127;
  float v = w1[(n * 128 + ic) * 9 + tap];
  w1p[((k >> 3) * 64 + n) * 8 + (k & 7)] = f2bf(v);
}

// ---------------- concat(ref,tgt) NCHW fp32 -> NHWC bf16 [b][y][x][128] ----------------
__global__ __launch_bounds__(256) void to_nhwc_kernel(
    const float* __restrict__ ref, const float* __restrict__ tgt,
    unsigned short* __restrict__ xin) {
  __shared__ unsigned short lds[32][132];
  const int b = blockIdx.z, y = blockIdx.y, x0 = blockIdx.x * 32;
  for (int idx = threadIdx.x; idx < 4096; idx += 256) {
    int ic = idx >> 5, px = idx & 31;
    const float* src = (ic < 64) ? ref : tgt;
    float v = src[(b * 64 + (ic & 63)) * PLANE + y * HW + x0 + px];
    lds[px][ic] = f2bf(v);
  }
  __syncthreads();
  for (int idx = threadIdx.x; idx < 4096; idx += 256) {
    int px = idx >> 7, ic = idx & 127;
    xin[((b * HW + y) * HW + x0 + px) * 128 + ic] = lds[px][ic];
  }
}

// ---------------- conv1 via bf16 MFMA: xin NHWC -> hmid fp32 NCHW (+bias, leaky) ----------------
// Block: 256 thr = 4 waves; tile 16x16 pixels x 64 oc. M=256 (16 frags), N=64 (4 frags).
// Wave w owns m-frags w*4..w*4+3 (spatial rows), all 4 n-frags. K = 9 taps * 128 ic.
__global__ __launch_bounds__(256) void conv1_mfma_kernel(
    const unsigned short* __restrict__ xin, const unsigned short* __restrict__ w1p,
    const float* __restrict__ b1, float* __restrict__ hmid) {
  __shared__ unsigned short tile[324 * 32];  // [yy*18+xx][ic32] = 20736 B
  const int bx = blockIdx.x * 16, by = blockIdx.y * 16, b = blockIdx.z;
  const int tid = threadIdx.x;
  const int lane = tid & 63, w = tid >> 6;
  const int l15 = lane & 15, lg = lane >> 4;

  f32x4 acc[4][4];
#pragma unroll
  for (int q = 0; q < 4; ++q)
#pragma unroll
    for (int nf = 0; nf < 4; ++nf)
      acc[q][nf] = (f32x4){0.f, 0.f, 0.f, 0.f};

  for (int c = 0; c < 4; ++c) {
    __syncthreads();  // previous tile fully consumed
    for (int i = tid; i < 1296; i += 256) {
      int pos = i >> 2, g = i & 3;
      int yy = pos / 18, xx = pos - yy * 18;
      int gy = by + yy - 1, gx = bx + xx - 1;
      uint4 v = make_uint4(0u, 0u, 0u, 0u);
      if ((unsigned)gy < 128u && (unsigned)gx < 128u)
        v = *(const uint4*)(xin + ((b * HW + gy) * HW + gx) * 128 + c * 32 + g * 8);
      *(uint4*)(tile + pos * 32 + g * 8) = v;
    }
    __syncthreads();

#pragma unroll
    for (int tap = 0; tap < 9; ++tap) {
      const int ty = tap / 3, tx = tap - ty * 3;
      bf16x8 afr[4];
#pragma unroll
      for (int q = 0; q < 4; ++q) {
        int py = w * 4 + q;
        afr[q] = *(const bf16x8*)(tile + ((py + ty) * 18 + l15 + tx) * 32 + lg * 8);
      }
      const int kb = tap * 16 + c * 4 + lg;
      bf16x8 bfr[4];
#pragma unroll
      for (int nf = 0; nf < 4; ++nf)
        bfr[nf] = *(const bf16x8*)(w1p + (kb * 64 + nf * 16 + l15) * 8);
#pragma unroll
      for (int q = 0; q < 4; ++q)
#pragma unroll
        for (int nf = 0; nf < 4; ++nf)
          acc[q][nf] = __builtin_amdgcn_mfma_f32_16x16x32_bf16(afr[q], bfr[nf], acc[q][nf], 0, 0, 0);
    }
  }

  // epilogue: D frag (q,nf): py = by + w*4 + q, px = bx + lg*4 + reg, oc = nf*16 + l15
  const int px0 = bx + lg * 4;
#pragma unroll
  for (int q = 0; q < 4; ++q) {
    const int py = by + w * 4 + q;
#pragma unroll
    for (int nf = 0; nf < 4; ++nf) {
      const int oc = nf * 16 + l15;
      const float bias = b1[oc];
      float4 o;
      float v0 = acc[q][nf][0] + bias;
      float v1 = acc[q][nf][1] + bias;
      float v2 = acc[q][nf][2] + bias;
      float v3 = acc[q][nf][3] + bias;
      o.x = (v0 >= 0.f) ? v0 : 0.1f * v0;
      o.y = (v1 >= 0.f) ? v1 : 0.1f * v1;
      o.z = (v2 >= 0.f) ? v2 : 0.1f * v2;
      o.w = (v3 >= 0.f) ? v3 : 0.1f * v3;
      *(float4*)(hmid + (b * 64 + oc) * PLANE + py * HW + px0) = o;
    }
  }
}

// ---------------- conv2: hmid [64ch] -> offsets [18ch] (fp32) ----------------
__global__ __launch_bounds__(256) void conv2_kernel(
    const float* __restrict__ hmid, const float* __restrict__ w2t,
    const float* __restrict__ b2, float* __restrict__ offs) {
  __shared__ float tile[16 * 324];
  const int bx = blockIdx.x * 16, by = blockIdx.y * 16, b = blockIdx.z;
  const int tx = threadIdx.x & 15, ty = threadIdx.x >> 4;

  float acc[18];
#pragma unroll
  for (int i = 0; i < 18; ++i) acc[i] = 0.f;

  for (int chunk = 0; chunk < 4; ++chunk) {
    const int cbase = chunk * 16;
    __syncthreads();
    for (int idx = threadIdx.x; idx < 16 * 324; idx += 256) {
      int icl = idx / 324;
      int rem = idx - icl * 324;
      int yy = rem / 18, xx = rem - yy * 18;
      int gy = by + yy - 1, gx = bx + xx - 1;
      float v = 0.f;
      if ((unsigned)gy < 128u && (unsigned)gx < 128u)
        v = hmid[(b * 64 + cbase + icl) * PLANE + gy * HW + gx];
      tile[idx] = v;
    }
    __syncthreads();
    const int ic0 = chunk * 16;
    for (int icl = 0; icl < 16; ++icl) {
      const float* wbase = w2t + ((ic0 + icl) * 9) * 18;
      const float* trow = tile + icl * 324;
#pragma unroll
      for (int k = 0; k < 9; ++k) {
        const int ky = k / 3, kx = k - ky * 3;
        float v = trow[(ty + ky) * 18 + tx + kx];
        const float* wp = wbase + k * 18;
#pragma unroll
        for (int o = 0; o < 18; ++o) acc[o] = fmaf(v, wp[o], acc[o]);
      }
    }
  }

  const int y = by + ty, x = bx + tx;
#pragma unroll
  for (int o = 0; o < 18; ++o)
    offs[(b * 18 + o) * PLANE + y * HW + x] = acc[o] + b2[o];
}

// ---------------- deformable conv: gather + 64x(64*9) matmul (fp32) ----------------
__global__ __launch_bounds__(256) void deform_kernel(
    const float* __restrict__ tgt, const float* __restrict__ offs,
    const float* __restrict__ wdt, float* __restrict__ out) {
  const int bx = blockIdx.x * 16, by = blockIdx.y * 16, b = blockIdx.z;
  const int tx = threadIdx.x & 15, ty = threadIdx.x >> 4;
  const int x = bx + tx, y = by + ty;

  float4 acc[16];
#pragma unroll
  for (int i = 0; i < 16; ++i) acc[i] = make_float4(0.f, 0.f, 0.f, 0.f);

  const float* tb = tgt + b * 64 * PLANE;

  for (int kk = 0; kk < 9; ++kk) {
    float dy = offs[(b * 18 + kk * 2) * PLANE + y * HW + x];
    float dx = offs[(b * 18 + kk * 2 + 1) * PLANE + y * HW + x];
    float ys = (float)(y + (kk / 3) - 1) + dy;
    float xs = (float)(x + (kk % 3) - 1) + dx;
    float y0f = floorf(ys), x0f = floorf(xs);
    float wy = ys - y0f, wx = xs - x0f;
    int y0 = (int)y0f, x0 = (int)x0f;
    int y1 = y0 + 1, x1 = x0 + 1;

    float vy0 = (y0 >= 0 && y0 < HW) ? 1.f : 0.f;
    float vy1 = (y1 >= 0 && y1 < HW) ? 1.f : 0.f;
    float vx0 = (x0 >= 0 && x0 < HW) ? 1.f : 0.f;
    float vx1 = (x1 >= 0 && x1 < HW) ? 1.f : 0.f;

    int y0c = min(max(y0, 0), HW - 1), y1c = min(max(y1, 0), HW - 1);
    int x0c = min(max(x0, 0), HW - 1), x1c = min(max(x1, 0), HW - 1);

    float w00 = (1.f - wy) * (1.f - wx) * vy0 * vx0;
    float w01 = (1.f - wy) * wx * vy0 * vx1;
    float w10 = wy * (1.f - wx) * vy1 * vx0;
    float w11 = wy * wx * vy1 * vx1;

    const float* p00 = tb + y0c * HW + x0c;
    const float* p01 = tb + y0c * HW + x1c;
    const float* p10 = tb + y1c * HW + x0c;
    const float* p11 = tb + y1c * HW + x1c;

    for (int ic = 0; ic < 64; ++ic) {
      int po = ic * PLANE;
      float v = w00 * p00[po] + w01 * p01[po] + w10 * p10[po] + w11 * p11[po];
      const float4* w4 = (const float4*)(wdt + (ic * 9 + kk) * 64);
#pragma unroll
      for (int o = 0; o < 16; ++o) {
        float4 w = w4[o];
        acc[o].x = fmaf(v, w.x, acc[o].x);
        acc[o].y = fmaf(v, w.y, acc[o].y);
        acc[o].z = fmaf(v, w.z, acc[o].z);
        acc[o].w = fmaf(v, w.w, acc[o].w);
      }
    }
  }

#pragma unroll
  for (int o = 0; o < 16; ++o) {
    float vals[4] = {acc[o].x, acc[o].y, acc[o].z, acc[o].w};
#pragma unroll
    for (int c = 0; c < 4; ++c) {
      int oc = o * 4 + c;
      out[(b * 64 + oc) * PLANE + y * HW + x] = vals[c];
    }
  }
}

extern "C" void kernel_launch(void* const* d_in, const int* in_sizes, int n_in,
                              void* d_out, int out_size, void* d_ws, size_t ws_size,
                              hipStream_t stream) {
  const float* ref = (const float*)d_in[0];
  const float* tgt = (const float*)d_in[1];
  const float* w1  = (const float*)d_in[2];
  const float* b1  = (const float*)d_in[3];
  const float* w2  = (const float*)d_in[4];
  const float* b2  = (const float*)d_in[5];
  const float* wd  = (const float*)d_in[6];

  // hmid (fp32, 33.5 MB) lives in d_out: written by conv1, read by conv2,
  // then fully overwritten by deform. All stream-ordered.
  float* hmid = (float*)d_out;
  float* out  = (float*)d_out;

  char* ws = (char*)d_ws;
  unsigned short* xin = (unsigned short*)ws;          // 33554432 B (dead after conv1)
  float* offs = (float*)ws;                           // 9437184 B, aliases dead xin
  unsigned short* w1p = (unsigned short*)(ws + 33554432);  // 147456 B
  float* w2t = (float*)(ws + 33701888);               // 41472 B
  float* wdt = (float*)(ws + 33743360);               // 147456 B; end = 33890816

  pack_w1_kernel<<<(1152 * 64 + 255) / 256, 256, 0, stream>>>(w1, w1p);
  transpose_w_kernel<<<(18 * 576 + 255) / 256, 256, 0, stream>>>(w2, w2t, 18, 576);
  transpose_w_kernel<<<(64 * 576 + 255) / 256, 256, 0, stream>>>(wd, wdt, 64, 576);

  to_nhwc_kernel<<<dim3(4, 128, 8), 256, 0, stream>>>(ref, tgt, xin);

  dim3 blk(256, 1, 1);
  dim3 grd(HW / 16, HW / 16, 8);
  conv1_mfma_kernel<<<grd, blk, 0, stream>>>(xin, w1p, b1, hmid);
  conv2_kernel<<<grd, blk, 0, stream>>>(hmid, w2t, b2, offs);
  deform_kernel<<<grd, blk, 0, stream>>>(tgt, offs, wdt, out);
}

// Round 3
// 202.799 us; speedup vs baseline: 3.3451x; 1.8687x over previous
//
#include <hip/hip_runtime.h>

#define HW 128
#define PLANE (HW * HW)

typedef __attribute__((ext_vector_type(8))) short bf16x8;
typedef __attribute__((ext_vector_type(4))) float f32x4;

__device__ __forceinline__ unsigned short f2bf(float f) {
  unsigned int u = __float_as_uint(f);
  unsigned int r = (u + 0x7fff + ((u >> 16) & 1)) >> 16;
  return (unsigned short)r;
}

// ---------------- weight transpose: src[o][ik] -> dst[ik][o] (fp32) ----------------
__global__ __launch_bounds__(256) void transpose_w_kernel(
    const float* __restrict__ src, float* __restrict__ dst, int O, int IK) {
  int idx = blockIdx.x * 256 + threadIdx.x;
  if (idx >= O * IK) return;
  int o = idx / IK, ik = idx - o * IK;
  dst[ik * O + o] = src[idx];
}

// ---------------- pack w1 fp32 [64][128][3][3] -> bf16 B'[(k>>3)*64+n][k&7], k=tap*128+ic ----------------
__global__ __launch_bounds__(256) void pack_w1_kernel(
    const float* __restrict__ w1, unsigned short* __restrict__ w1p) {
  int idx = blockIdx.x * 256 + threadIdx.x;
  if (idx >= 1152 * 64) return;
  int k = idx >> 6, n = idx & 63;
  int tap = k >> 7, ic = k & 127;
  float v = w1[(n * 128 + ic) * 9 + tap];
  w1p[((k >> 3) * 64 + n) * 8 + (k & 7)] = f2bf(v);
}

// ---------------- pack wd fp32 [64][64][3][3] -> bf16 B'[(k>>3)*64+n][k&7], k=tap*64+ic ----------------
__global__ __launch_bounds__(256) void pack_wd_kernel(
    const float* __restrict__ wd, unsigned short* __restrict__ wdp) {
  int idx = blockIdx.x * 256 + threadIdx.x;
  if (idx >= 576 * 64) return;
  int k = idx >> 6, n = idx & 63;
  int kk = k >> 6, ic = k & 63;
  float v = wd[(n * 64 + ic) * 9 + kk];
  wdp[((k >> 3) * 64 + n) * 8 + (k & 7)] = f2bf(v);
}

// ---------------- concat(ref,tgt) NCHW fp32 -> NHWC bf16 [b][y][x][128] ----------------
__global__ __launch_bounds__(256) void to_nhwc_kernel(
    const float* __restrict__ ref, const float* __restrict__ tgt,
    unsigned short* __restrict__ xin) {
  __shared__ unsigned short lds[32][132];
  const int b = blockIdx.z, y = blockIdx.y, x0 = blockIdx.x * 32;
  for (int idx = threadIdx.x; idx < 4096; idx += 256) {
    int ic = idx >> 5, px = idx & 31;
    const float* src = (ic < 64) ? ref : tgt;
    float v = src[(b * 64 + (ic & 63)) * PLANE + y * HW + x0 + px];
    lds[px][ic] = f2bf(v);
  }
  __syncthreads();
  for (int idx = threadIdx.x; idx < 4096; idx += 256) {
    int px = idx >> 7, ic = idx & 127;
    xin[((b * HW + y) * HW + x0 + px) * 128 + ic] = lds[px][ic];
  }
}

// ---------------- conv1 via bf16 MFMA: xin NHWC -> hmid fp32 NCHW (+bias, leaky) ----------------
__global__ __launch_bounds__(256) void conv1_mfma_kernel(
    const unsigned short* __restrict__ xin, const unsigned short* __restrict__ w1p,
    const float* __restrict__ b1, float* __restrict__ hmid) {
  __shared__ unsigned short tile[324 * 32];  // [yy*18+xx][ic32] = 20736 B
  const int bx = blockIdx.x * 16, by = blockIdx.y * 16, b = blockIdx.z;
  const int tid = threadIdx.x;
  const int lane = tid & 63, w = tid >> 6;
  const int l15 = lane & 15, lg = lane >> 4;

  f32x4 acc[4][4];
#pragma unroll
  for (int q = 0; q < 4; ++q)
#pragma unroll
    for (int nf = 0; nf < 4; ++nf)
      acc[q][nf] = (f32x4){0.f, 0.f, 0.f, 0.f};

  for (int c = 0; c < 4; ++c) {
    __syncthreads();
    for (int i = tid; i < 1296; i += 256) {
      int pos = i >> 2, g = i & 3;
      int yy = pos / 18, xx = pos - yy * 18;
      int gy = by + yy - 1, gx = bx + xx - 1;
      uint4 v = make_uint4(0u, 0u, 0u, 0u);
      if ((unsigned)gy < 128u && (unsigned)gx < 128u)
        v = *(const uint4*)(xin + ((b * HW + gy) * HW + gx) * 128 + c * 32 + g * 8);
      *(uint4*)(tile + pos * 32 + g * 8) = v;
    }
    __syncthreads();

#pragma unroll
    for (int tap = 0; tap < 9; ++tap) {
      const int ty = tap / 3, tx = tap - ty * 3;
      bf16x8 afr[4];
#pragma unroll
      for (int q = 0; q < 4; ++q) {
        int py = w * 4 + q;
        afr[q] = *(const bf16x8*)(tile + ((py + ty) * 18 + l15 + tx) * 32 + lg * 8);
      }
      const int kb = tap * 16 + c * 4 + lg;
      bf16x8 bfr[4];
#pragma unroll
      for (int nf = 0; nf < 4; ++nf)
        bfr[nf] = *(const bf16x8*)(w1p + (kb * 64 + nf * 16 + l15) * 8);
#pragma unroll
      for (int q = 0; q < 4; ++q)
#pragma unroll
        for (int nf = 0; nf < 4; ++nf)
          acc[q][nf] = __builtin_amdgcn_mfma_f32_16x16x32_bf16(afr[q], bfr[nf], acc[q][nf], 0, 0, 0);
    }
  }

  const int px0 = bx + lg * 4;
#pragma unroll
  for (int q = 0; q < 4; ++q) {
    const int py = by + w * 4 + q;
#pragma unroll
    for (int nf = 0; nf < 4; ++nf) {
      const int oc = nf * 16 + l15;
      const float bias = b1[oc];
      float4 o;
      float v0 = acc[q][nf][0] + bias;
      float v1 = acc[q][nf][1] + bias;
      float v2 = acc[q][nf][2] + bias;
      float v3 = acc[q][nf][3] + bias;
      o.x = (v0 >= 0.f) ? v0 : 0.1f * v0;
      o.y = (v1 >= 0.f) ? v1 : 0.1f * v1;
      o.z = (v2 >= 0.f) ? v2 : 0.1f * v2;
      o.w = (v3 >= 0.f) ? v3 : 0.1f * v3;
      *(float4*)(hmid + (b * 64 + oc) * PLANE + py * HW + px0) = o;
    }
  }
}

// ---------------- conv2: hmid [64ch] -> offsets [18ch] (fp32) ----------------
__global__ __launch_bounds__(256) void conv2_kernel(
    const float* __restrict__ hmid, const float* __restrict__ w2t,
    const float* __restrict__ b2, float* __restrict__ offs) {
  __shared__ float tile[16 * 324];
  const int bx = blockIdx.x * 16, by = blockIdx.y * 16, b = blockIdx.z;
  const int tx = threadIdx.x & 15, ty = threadIdx.x >> 4;

  float acc[18];
#pragma unroll
  for (int i = 0; i < 18; ++i) acc[i] = 0.f;

  for (int chunk = 0; chunk < 4; ++chunk) {
    const int cbase = chunk * 16;
    __syncthreads();
    for (int idx = threadIdx.x; idx < 16 * 324; idx += 256) {
      int icl = idx / 324;
      int rem = idx - icl * 324;
      int yy = rem / 18, xx = rem - yy * 18;
      int gy = by + yy - 1, gx = bx + xx - 1;
      float v = 0.f;
      if ((unsigned)gy < 128u && (unsigned)gx < 128u)
        v = hmid[(b * 64 + cbase + icl) * PLANE + gy * HW + gx];
      tile[idx] = v;
    }
    __syncthreads();
    const int ic0 = chunk * 16;
    for (int icl = 0; icl < 16; ++icl) {
      const float* wbase = w2t + ((ic0 + icl) * 9) * 18;
      const float* trow = tile + icl * 324;
#pragma unroll
      for (int k = 0; k < 9; ++k) {
        const int ky = k / 3, kx = k - ky * 3;
        float v = trow[(ty + ky) * 18 + tx + kx];
        const float* wp = wbase + k * 18;
#pragma unroll
        for (int o = 0; o < 18; ++o) acc[o] = fmaf(v, wp[o], acc[o]);
      }
    }
  }

  const int y = by + ty, x = bx + tx;
#pragma unroll
  for (int o = 0; o < 18; ++o)
    offs[(b * 18 + o) * PLANE + y * HW + x] = acc[o] + b2[o];
}

__device__ __forceinline__ unsigned int blend2(
    unsigned int a, unsigned int b, unsigned int c, unsigned int d,
    float w00, float w01, float w10, float w11) {
  float alo = __uint_as_float(a << 16), ahi = __uint_as_float(a & 0xffff0000u);
  float blo = __uint_as_float(b << 16), bhi = __uint_as_float(b & 0xffff0000u);
  float clo = __uint_as_float(c << 16), chi = __uint_as_float(c & 0xffff0000u);
  float dlo = __uint_as_float(d << 16), dhi = __uint_as_float(d & 0xffff0000u);
  float vlo = fmaf(w11, dlo, fmaf(w10, clo, fmaf(w01, blo, w00 * alo)));
  float vhi = fmaf(w11, dhi, fmaf(w10, chi, fmaf(w01, bhi, w00 * ahi)));
  return (unsigned int)f2bf(vlo) | ((unsigned int)f2bf(vhi) << 16);
}

// ---------------- deformable conv via bf16 MFMA ----------------
// Block 256 thr = 4 waves; tile 16x16 px x 64 oc. K = 9 taps x 64 ic.
// Per tap: each thread bilinear-samples its pixel's 64 ic from xin (tgt half,
// NHWC bf16) into LDS [256 px][64 ic] (XOR-swizzled), then 2 MFMA K-steps.
__global__ __launch_bounds__(256) void deform_mfma_kernel(
    const unsigned short* __restrict__ xin, const float* __restrict__ offs,
    const unsigned short* __restrict__ wdp, float* __restrict__ out) {
  __shared__ unsigned short samp[256 * 64];  // 32 KiB
  const int bx = blockIdx.x * 16, by = blockIdx.y * 16, b = blockIdx.z;
  const int tid = threadIdx.x;
  const int lane = tid & 63, w = tid >> 6;
  const int l15 = lane & 15, lg = lane >> 4;
  const int tx = tid & 15, ty = tid >> 4;
  const int x = bx + tx, y = by + ty;

  f32x4 acc[4][4];
#pragma unroll
  for (int q = 0; q < 4; ++q)
#pragma unroll
    for (int nf = 0; nf < 4; ++nf)
      acc[q][nf] = (f32x4){0.f, 0.f, 0.f, 0.f};

  const float* offb = offs + (b * 18) * PLANE + y * HW + x;
  const unsigned short* tb = xin + (size_t)(b * HW) * HW * 128 + 64;  // tgt half
  unsigned short* sb = samp + (ty * 16 + tx) * 64;
  const int swz = (tx & 7) << 3;       // short-unit XOR for writes
  const int rswz = (l15 & 7) << 3;     // short-unit XOR for frag reads

  for (int kk = 0; kk < 9; ++kk) {
    // ---- sample this thread's pixel, 64 ic ----
    float dy = offb[(kk * 2) * PLANE];
    float dx = offb[(kk * 2 + 1) * PLANE];
    float ys = (float)(y + (kk / 3) - 1) + dy;
    float xs = (float)(x + (kk % 3) - 1) + dx;
    float y0f = floorf(ys), x0f = floorf(xs);
    float wy = ys - y0f, wx = xs - x0f;
    int y0 = (int)y0f, x0i = (int)x0f;
    int y1 = y0 + 1, x1 = x0i + 1;
    float vy0 = (y0 >= 0 && y0 < HW) ? 1.f : 0.f;
    float vy1 = (y1 >= 0 && y1 < HW) ? 1.f : 0.f;
    float vx0 = (x0i >= 0 && x0i < HW) ? 1.f : 0.f;
    float vx1 = (x1 >= 0 && x1 < HW) ? 1.f : 0.f;
    int y0c = min(max(y0, 0), HW - 1), y1c = min(max(y1, 0), HW - 1);
    int x0c = min(max(x0i, 0), HW - 1), x1c = min(max(x1, 0), HW - 1);
    float w00 = (1.f - wy) * (1.f - wx) * vy0 * vx0;
    float w01 = (1.f - wy) * wx * vy0 * vx1;
    float w10 = wy * (1.f - wx) * vy1 * vx0;
    float w11 = wy * wx * vy1 * vx1;
    const unsigned short* p00 = tb + (y0c * HW + x0c) * 128;
    const unsigned short* p01 = tb + (y0c * HW + x1c) * 128;
    const unsigned short* p10 = tb + (y1c * HW + x0c) * 128;
    const unsigned short* p11 = tb + (y1c * HW + x1c) * 128;

    __syncthreads();  // previous tap's frag reads complete
#pragma unroll
    for (int g = 0; g < 8; ++g) {
      uint4 av = *(const uint4*)(p00 + g * 8);
      uint4 bv = *(const uint4*)(p01 + g * 8);
      uint4 cv = *(const uint4*)(p10 + g * 8);
      uint4 dv = *(const uint4*)(p11 + g * 8);
      uint4 r;
      r.x = blend2(av.x, bv.x, cv.x, dv.x, w00, w01, w10, w11);
      r.y = blend2(av.y, bv.y, cv.y, dv.y, w00, w01, w10, w11);
      r.z = blend2(av.z, bv.z, cv.z, dv.z, w00, w01, w10, w11);
      r.w = blend2(av.w, bv.w, cv.w, dv.w, w00, w01, w10, w11);
      *(uint4*)(sb + ((g * 8) ^ swz)) = r;
    }
    __syncthreads();  // tile ready

    // ---- 2 MFMA K-steps (32 ic each) ----
#pragma unroll
    for (int ks = 0; ks < 2; ++ks) {
      bf16x8 afr[4];
#pragma unroll
      for (int q = 0; q < 4; ++q)
        afr[q] = *(const bf16x8*)(samp + ((w * 4 + q) * 16 + l15) * 64 +
                                  (((ks * 32) + lg * 8) ^ rswz));
      const int kb = kk * 8 + ks * 4 + lg;
      bf16x8 bfr[4];
#pragma unroll
      for (int nf = 0; nf < 4; ++nf)
        bfr[nf] = *(const bf16x8*)(wdp + (kb * 64 + nf * 16 + l15) * 8);
#pragma unroll
      for (int q = 0; q < 4; ++q)
#pragma unroll
        for (int nf = 0; nf < 4; ++nf)
          acc[q][nf] = __builtin_amdgcn_mfma_f32_16x16x32_bf16(afr[q], bfr[nf], acc[q][nf], 0, 0, 0);
    }
  }

  const int px0 = bx + lg * 4;
#pragma unroll
  for (int q = 0; q < 4; ++q) {
    const int py = by + w * 4 + q;
#pragma unroll
    for (int nf = 0; nf < 4; ++nf) {
      const int oc = nf * 16 + l15;
      float4 o;
      o.x = acc[q][nf][0];
      o.y = acc[q][nf][1];
      o.z = acc[q][nf][2];
      o.w = acc[q][nf][3];
      *(float4*)(out + (b * 64 + oc) * PLANE + py * HW + px0) = o;
    }
  }
}

extern "C" void kernel_launch(void* const* d_in, const int* in_sizes, int n_in,
                              void* d_out, int out_size, void* d_ws, size_t ws_size,
                              hipStream_t stream) {
  const float* ref = (const float*)d_in[0];
  const float* tgt = (const float*)d_in[1];
  const float* w1  = (const float*)d_in[2];
  const float* b1  = (const float*)d_in[3];
  const float* w2  = (const float*)d_in[4];
  const float* b2  = (const float*)d_in[5];
  const float* wd  = (const float*)d_in[6];

  // hmid (fp32, 33.5 MB) lives in d_out: written by conv1, read by conv2,
  // then fully overwritten by deform (which reads only xin/offs). Stream-ordered.
  float* hmid = (float*)d_out;
  float* out  = (float*)d_out;

  char* ws = (char*)d_ws;
  unsigned short* xin = (unsigned short*)ws;               // 33554432 B, alive thru deform
  float* offs = (float*)(ws + 33554432);                   // 9437184 B
  unsigned short* w1p = (unsigned short*)(ws + 42991616);  // 147456 B
  float* w2t = (float*)(ws + 43139072);                    // 41472 B
  unsigned short* wdp = (unsigned short*)(ws + 43180544);  // 73728 B; end = 43254272

  pack_w1_kernel<<<(1152 * 64 + 255) / 256, 256, 0, stream>>>(w1, w1p);
  transpose_w_kernel<<<(18 * 576 + 255) / 256, 256, 0, stream>>>(w2, w2t, 18, 576);
  pack_wd_kernel<<<(576 * 64 + 255) / 256, 256, 0, stream>>>(wd, wdp);

  to_nhwc_kernel<<<dim3(4, 128, 8), 256, 0, stream>>>(ref, tgt, xin);

  dim3 blk(256, 1, 1);
  dim3 grd(HW / 16, HW / 16, 8);
  conv1_mfma_kernel<<<grd, blk, 0, stream>>>(xin, w1p, b1, hmid);
  conv2_kernel<<<grd, blk, 0, stream>>>(hmid, w2t, b2, offs);
  deform_mfma_kernel<<<grd, blk, 0, stream>>>(xin, offs, wdp, out);
}

// Round 4
// 143.031 us; speedup vs baseline: 4.7429x; 1.4179x over previous
//
#include <hip/hip_runtime.h>
#include <hip/hip_fp16.h>

#define HW 128
#define PLANE (HW * HW)

typedef __attribute__((ext_vector_type(8))) _Float16 f16x8;
typedef __attribute__((ext_vector_type(4))) float f32x4;

__device__ __forceinline__ unsigned short f2h(float f) {
  return __half_as_ushort(__float2half(f));
}

// ---------------- pack w1 fp32 [64][128][3][3] -> fp16 A'[(k>>3)*64+n][k&7], k=tap*128+ic ----------------
__global__ __launch_bounds__(256) void pack_w1_kernel(
    const float* __restrict__ w1, unsigned short* __restrict__ w1p) {
  int idx = blockIdx.x * 256 + threadIdx.x;
  if (idx >= 1152 * 64) return;
  int k = idx >> 6, n = idx & 63;
  int tap = k >> 7, ic = k & 127;
  w1p[((k >> 3) * 64 + n) * 8 + (k & 7)] = f2h(w1[(n * 128 + ic) * 9 + tap]);
}

// ---------------- pack w2 fp32 [18][64][3][3] -> fp16 B'[(k>>3)*32+n][k&7], k=tap*64+ic, N padded to 32 ----------------
__global__ __launch_bounds__(256) void pack_w2_kernel(
    const float* __restrict__ w2, unsigned short* __restrict__ w2p) {
  int idx = blockIdx.x * 256 + threadIdx.x;
  if (idx >= 576 * 32) return;
  int k = idx >> 5, n = idx & 31;
  int tap = k >> 6, ic = k & 63;
  float v = (n < 18) ? w2[(n * 64 + ic) * 9 + tap] : 0.f;
  w2p[((k >> 3) * 32 + n) * 8 + (k & 7)] = f2h(v);
}

// ---------------- pack wd fp32 [64][64][3][3] -> fp16 B'[(k>>3)*64+n][k&7], k=tap*64+ic ----------------
__global__ __launch_bounds__(256) void pack_wd_kernel(
    const float* __restrict__ wd, unsigned short* __restrict__ wdp) {
  int idx = blockIdx.x * 256 + threadIdx.x;
  if (idx >= 576 * 64) return;
  int k = idx >> 6, n = idx & 63;
  int tap = k >> 6, ic = k & 63;
  wdp[((k >> 3) * 64 + n) * 8 + (k & 7)] = f2h(wd[(n * 64 + ic) * 9 + tap]);
}

// ---------------- ref,tgt NCHW fp32 -> NHWC fp16: xref [b][y][x][64], xtgt [b][y][x][64] ----------------
__global__ __launch_bounds__(256) void to_nhwc_kernel(
    const float* __restrict__ ref, const float* __restrict__ tgt,
    unsigned short* __restrict__ xref, unsigned short* __restrict__ xtgt) {
  __shared__ unsigned short lds[32][136];
  const int b = blockIdx.z, y = blockIdx.y, x0 = blockIdx.x * 32;
  for (int idx = threadIdx.x; idx < 4096; idx += 256) {
    int ic = idx >> 5, px = idx & 31;
    const float* src = (ic < 64) ? ref : tgt;
    lds[px][ic] = f2h(src[(b * 64 + (ic & 63)) * PLANE + y * HW + x0 + px]);
  }
  __syncthreads();
  for (int idx = threadIdx.x; idx < 512; idx += 256) {
    int px = idx >> 4, g = idx & 15;
    uint4 v = *(const uint4*)&lds[px][g * 8];
    size_t base = ((size_t)(b * HW + y) * HW + x0 + px) * 64;
    if (g < 8)
      *(uint4*)(xref + base + g * 8) = v;
    else
      *(uint4*)(xtgt + base + (g - 8) * 8) = v;
  }
}

// ---------------- conv1 via fp16 MFMA: (xref,xtgt) NHWC -> hmid fp16 NHWC (+bias, leaky) ----------------
// 512 thr = 8 waves; tile 16x16 px x 64 oc. Operand-swapped: A=weights (M=oc), B=pixels (N=x).
// Wave w owns y-rows w*2+q (q=0,1); acc[mf][q], mf = oc-frag.
__global__ __launch_bounds__(512) void conv1_mfma_kernel(
    const unsigned short* __restrict__ xref, const unsigned short* __restrict__ xtgt,
    const unsigned short* __restrict__ w1p, const float* __restrict__ b1,
    unsigned short* __restrict__ hm) {
  __shared__ unsigned short tileH[324 * 64];  // 41472 B, XOR-swizzled rows
  const int bx = blockIdx.x * 16, by = blockIdx.y * 16, b = blockIdx.z;
  const int tid = threadIdx.x, lane = tid & 63, w = tid >> 6;
  const int l15 = lane & 15, lg = lane >> 4;

  f32x4 acc[4][2];
#pragma unroll
  for (int mf = 0; mf < 4; ++mf)
#pragma unroll
    for (int q = 0; q < 2; ++q) acc[mf][q] = (f32x4){0.f, 0.f, 0.f, 0.f};

  for (int c = 0; c < 2; ++c) {
    const unsigned short* src = c ? xtgt : xref;
    __syncthreads();
    for (int i = tid; i < 2592; i += 512) {
      int pos = i >> 3, g = i & 7;
      int yy = pos / 18, xx = pos - yy * 18;
      int gy = by + yy - 1, gx = bx + xx - 1;
      uint4 v = make_uint4(0u, 0u, 0u, 0u);
      if ((unsigned)gy < 128u && (unsigned)gx < 128u)
        v = *(const uint4*)(src + ((size_t)(b * HW + gy) * HW + gx) * 64 + g * 8);
      *(uint4*)(tileH + pos * 64 + ((g * 8) ^ ((pos & 7) << 3))) = v;
    }
    __syncthreads();

#pragma unroll
    for (int tap = 0; tap < 9; ++tap) {
      const int ty = tap / 3, tx = tap - ty * 3;
#pragma unroll
      for (int ks = 0; ks < 2; ++ks) {
        f16x8 ap[2];
#pragma unroll
        for (int q = 0; q < 2; ++q) {
          int pos = (w * 2 + q + ty) * 18 + l15 + tx;
          ap[q] = *(const f16x8*)(tileH + pos * 64 + ((ks * 32 + lg * 8) ^ ((pos & 7) << 3)));
        }
        const int kb = tap * 16 + c * 8 + ks * 4 + lg;
        f16x8 aw[4];
#pragma unroll
        for (int mf = 0; mf < 4; ++mf)
          aw[mf] = *(const f16x8*)(w1p + (kb * 64 + mf * 16 + l15) * 8);
#pragma unroll
        for (int mf = 0; mf < 4; ++mf)
#pragma unroll
          for (int q = 0; q < 2; ++q)
            acc[mf][q] = __builtin_amdgcn_mfma_f32_16x16x32_f16(aw[mf], ap[q], acc[mf][q], 0, 0, 0);
      }
    }
  }

  // D: row = oc_in16 = lg*4+reg, col = x = l15. Store 4 oc (8B) per lane, NHWC.
#pragma unroll
  for (int mf = 0; mf < 4; ++mf) {
    const float4 bv = ((const float4*)b1)[mf * 4 + lg];
#pragma unroll
    for (int q = 0; q < 2; ++q) {
      const int y = by + w * 2 + q;
      float v0 = acc[mf][q][0] + bv.x;
      float v1 = acc[mf][q][1] + bv.y;
      float v2 = acc[mf][q][2] + bv.z;
      float v3 = acc[mf][q][3] + bv.w;
      v0 = (v0 >= 0.f) ? v0 : 0.1f * v0;
      v1 = (v1 >= 0.f) ? v1 : 0.1f * v1;
      v2 = (v2 >= 0.f) ? v2 : 0.1f * v2;
      v3 = (v3 >= 0.f) ? v3 : 0.1f * v3;
      ushort4 s;
      s.x = f2h(v0); s.y = f2h(v1); s.z = f2h(v2); s.w = f2h(v3);
      *(ushort4*)(hm + ((size_t)(b * HW + y) * HW + bx + l15) * 64 + mf * 16 + lg * 4) = s;
    }
  }
}

__device__ __forceinline__ uint4 blend4(uint4 a, uint4 b, uint4 c, uint4 d,
                                        __half2 h00, __half2 h01, __half2 h10, __half2 h11) {
  union U { uint4 u; __half2 h[4]; };
  U A, B, C, D, R;
  A.u = a; B.u = b; C.u = c; D.u = d;
#pragma unroll
  for (int i = 0; i < 4; ++i)
    R.h[i] = __hfma2(D.h[i], h11, __hfma2(C.h[i], h10, __hfma2(B.h[i], h01, __hmul2(A.h[i], h00))));
  return R.u;
}

// ---------------- fused conv2 (MFMA) + deformable conv (MFMA) ----------------
// 512 thr = 8 waves per 16x16 px tile.
// Phase A: stage hmid halo -> LDS, conv2 MFMA (N=32, 18 valid) -> offsL in LDS.
// Phase B: per tap: bilinear-sample xtgt (half2 math) -> samp LDS -> MFMA with wd.
__global__ __launch_bounds__(512) void fused_kernel(
    const unsigned short* __restrict__ hm, const unsigned short* __restrict__ xtgt,
    const unsigned short* __restrict__ w2p, const float* __restrict__ b2,
    const unsigned short* __restrict__ wdp, float* __restrict__ out) {
  __shared__ unsigned short tileH[324 * 64];  // 41472 B; samp aliases first 32768 B
  __shared__ float offsL[256 * 21];           // 21504 B
  unsigned short* samp = tileH;

  const int bx = blockIdx.x * 16, by = blockIdx.y * 16, b = blockIdx.z;
  const int tid = threadIdx.x, lane = tid & 63, w = tid >> 6;
  const int l15 = lane & 15, lg = lane >> 4;

  // ---- phase A: stage hmid halo ----
  for (int i = tid; i < 2592; i += 512) {
    int pos = i >> 3, g = i & 7;
    int yy = pos / 18, xx = pos - yy * 18;
    int gy = by + yy - 1, gx = bx + xx - 1;
    uint4 v = make_uint4(0u, 0u, 0u, 0u);
    if ((unsigned)gy < 128u && (unsigned)gx < 128u)
      v = *(const uint4*)(hm + ((size_t)(b * HW + gy) * HW + gx) * 64 + g * 8);
    *(uint4*)(tileH + pos * 64 + ((g * 8) ^ ((pos & 7) << 3))) = v;
  }
  __syncthreads();

  // ---- conv2 MFMA: A=pixels (M=x), B=w2p (N=32) ----
  f32x4 acc2[2][2];
#pragma unroll
  for (int q = 0; q < 2; ++q)
#pragma unroll
    for (int nf = 0; nf < 2; ++nf) acc2[q][nf] = (f32x4){0.f, 0.f, 0.f, 0.f};

#pragma unroll
  for (int tap = 0; tap < 9; ++tap) {
    const int ty = tap / 3, tx = tap - ty * 3;
#pragma unroll
    for (int ks = 0; ks < 2; ++ks) {
      f16x8 ap[2];
#pragma unroll
      for (int q = 0; q < 2; ++q) {
        int pos = (w * 2 + q + ty) * 18 + l15 + tx;
        ap[q] = *(const f16x8*)(tileH + pos * 64 + ((ks * 32 + lg * 8) ^ ((pos & 7) << 3)));
      }
      const int kb = tap * 8 + ks * 4 + lg;
      f16x8 bw[2];
#pragma unroll
      for (int nf = 0; nf < 2; ++nf)
        bw[nf] = *(const f16x8*)(w2p + (kb * 32 + nf * 16 + l15) * 8);
#pragma unroll
      for (int q = 0; q < 2; ++q)
#pragma unroll
        for (int nf = 0; nf < 2; ++nf)
          acc2[q][nf] = __builtin_amdgcn_mfma_f32_16x16x32_f16(ap[q], bw[nf], acc2[q][nf], 0, 0, 0);
    }
  }
  // offsets -> LDS. D: row = x = lg*4+reg, col = oc = nf*16+l15.
#pragma unroll
  for (int nf = 0; nf < 2; ++nf) {
    const int oc = nf * 16 + l15;
    if (oc < 18) {
      const float bias = b2[oc];
#pragma unroll
      for (int q = 0; q < 2; ++q)
#pragma unroll
        for (int reg = 0; reg < 4; ++reg) {
          int px = (w * 2 + q) * 16 + lg * 4 + reg;
          offsL[px * 21 + oc] = acc2[q][nf][reg] + bias;
        }
    }
  }
  __syncthreads();

  // ---- phase B: deform ----
  const int px_self = tid & 255, ich = tid >> 8;  // thread-halves split ic 0..31 / 32..63
  const int txp = px_self & 15, typ = px_self >> 4;
  const int x = bx + txp, y = by + typ;
  const unsigned short* tb = xtgt + (size_t)b * PLANE * 64 + ich * 32;
  unsigned short* sb = samp + px_self * 64;
  const int swz = (txp & 7) << 3;
  const int rswz = (l15 & 7) << 3;

  f32x4 acc[2][4];
#pragma unroll
  for (int q = 0; q < 2; ++q)
#pragma unroll
    for (int nf = 0; nf < 4; ++nf) acc[q][nf] = (f32x4){0.f, 0.f, 0.f, 0.f};

  for (int kk = 0; kk < 9; ++kk) {
    float dy = offsL[px_self * 21 + kk * 2];
    float dx = offsL[px_self * 21 + kk * 2 + 1];
    float ys = (float)(y + (kk / 3) - 1) + dy;
    float xs = (float)(x + (kk % 3) - 1) + dx;
    float y0f = floorf(ys), x0f = floorf(xs);
    float wy = ys - y0f, wx = xs - x0f;
    int y0 = (int)y0f, x0i = (int)x0f;
    int y1 = y0 + 1, x1 = x0i + 1;
    float vy0 = (y0 >= 0 && y0 < HW) ? 1.f : 0.f;
    float vy1 = (y1 >= 0 && y1 < HW) ? 1.f : 0.f;
    float vx0 = (x0i >= 0 && x0i < HW) ? 1.f : 0.f;
    float vx1 = (x1 >= 0 && x1 < HW) ? 1.f : 0.f;
    int y0c = min(max(y0, 0), HW - 1), y1c = min(max(y1, 0), HW - 1);
    int x0c = min(max(x0i, 0), HW - 1), x1c = min(max(x1, 0), HW - 1);
    __half2 h00 = __float2half2_rn((1.f - wy) * (1.f - wx) * vy0 * vx0);
    __half2 h01 = __float2half2_rn((1.f - wy) * wx * vy0 * vx1);
    __half2 h10 = __float2half2_rn(wy * (1.f - wx) * vy1 * vx0);
    __half2 h11 = __float2half2_rn(wy * wx * vy1 * vx1);
    const unsigned short* p00 = tb + (y0c * HW + x0c) * 64;
    const unsigned short* p01 = tb + (y0c * HW + x1c) * 64;
    const unsigned short* p10 = tb + (y1c * HW + x0c) * 64;
    const unsigned short* p11 = tb + (y1c * HW + x1c) * 64;

    __syncthreads();  // previous tap's frag reads done (kk=0: phase-A tileH reads done)
#pragma unroll
    for (int g = 0; g < 4; ++g) {
      uint4 av = *(const uint4*)(p00 + g * 8);
      uint4 bv = *(const uint4*)(p01 + g * 8);
      uint4 cv = *(const uint4*)(p10 + g * 8);
      uint4 dv = *(const uint4*)(p11 + g * 8);
      uint4 r = blend4(av, bv, cv, dv, h00, h01, h10, h11);
      *(uint4*)(sb + ((ich * 32 + g * 8) ^ swz)) = r;
    }
    __syncthreads();  // tile ready

#pragma unroll
    for (int ks = 0; ks < 2; ++ks) {
      f16x8 af[2];
#pragma unroll
      for (int q = 0; q < 2; ++q)
        af[q] = *(const f16x8*)(samp + ((w * 2 + q) * 16 + l15) * 64 + ((ks * 32 + lg * 8) ^ rswz));
      const int kb = kk * 8 + ks * 4 + lg;
      f16x8 bw[4];
#pragma unroll
      for (int nf = 0; nf < 4; ++nf)
        bw[nf] = *(const f16x8*)(wdp + (kb * 64 + nf * 16 + l15) * 8);
#pragma unroll
      for (int q = 0; q < 2; ++q)
#pragma unroll
        for (int nf = 0; nf < 4; ++nf)
          acc[q][nf] = __builtin_amdgcn_mfma_f32_16x16x32_f16(af[q], bw[nf], acc[q][nf], 0, 0, 0);
    }
  }

  const int px0 = bx + lg * 4;
#pragma unroll
  for (int q = 0; q < 2; ++q) {
    const int py = by + w * 2 + q;
#pragma unroll
    for (int nf = 0; nf < 4; ++nf) {
      const int oc = nf * 16 + l15;
      float4 o;
      o.x = acc[q][nf][0];
      o.y = acc[q][nf][1];
      o.z = acc[q][nf][2];
      o.w = acc[q][nf][3];
      *(float4*)(out + (size_t)(b * 64 + oc) * PLANE + py * HW + px0) = o;
    }
  }
}

extern "C" void kernel_launch(void* const* d_in, const int* in_sizes, int n_in,
                              void* d_out, int out_size, void* d_ws, size_t ws_size,
                              hipStream_t stream) {
  const float* ref = (const float*)d_in[0];
  const float* tgt = (const float*)d_in[1];
  const float* w1  = (const float*)d_in[2];
  const float* b1  = (const float*)d_in[3];
  const float* w2  = (const float*)d_in[4];
  const float* b2  = (const float*)d_in[5];
  const float* wd  = (const float*)d_in[6];

  // xref (fp16 NHWC, 16.8 MB) lives in d_out: written by to_nhwc, read by conv1,
  // dead before fused_kernel overwrites d_out with the final output. Stream-ordered.
  unsigned short* xref = (unsigned short*)d_out;
  float* out = (float*)d_out;

  char* ws = (char*)d_ws;
  unsigned short* xtgt = (unsigned short*)ws;                   // 16777216 B
  unsigned short* hmid = (unsigned short*)(ws + 16777216);      // 16777216 B
  unsigned short* w1p  = (unsigned short*)(ws + 33554432);      // 147456 B
  unsigned short* w2p  = (unsigned short*)(ws + 33701888);      // 36864 B
  unsigned short* wdp  = (unsigned short*)(ws + 33738752);      // 73728 B; end = 33812480

  pack_w1_kernel<<<288, 256, 0, stream>>>(w1, w1p);
  pack_w2_kernel<<<72, 256, 0, stream>>>(w2, w2p);
  pack_wd_kernel<<<144, 256, 0, stream>>>(wd, wdp);

  to_nhwc_kernel<<<dim3(4, 128, 8), 256, 0, stream>>>(ref, tgt, xref, xtgt);

  dim3 grd(HW / 16, HW / 16, 8);
  conv1_mfma_kernel<<<grd, 512, 0, stream>>>(xref, xtgt, w1p, b1, hmid);
  fused_kernel<<<grd, 512, 0, stream>>>(hmid, xtgt, w2p, b2, wdp, out);
}